// Round 1
// baseline (60.616 us; speedup 1.0000x reference)
//
#include <hip/hip_runtime.h>
#include <math.h>

#define HH 256
#define WW 256
#define NPIX 65536
#define KP 512
#define NCAND 1024
#define CTOT 192

__device__ __forceinline__ float sigmoidf_(float x) {
    return 1.0f / (1.0f + expf(-x));
}

// ---------------- phase 1: per-window NMS candidates ----------------
// grid 1024 x 256 threads; each wave (64 lanes) reduces one 8x8 window.
__global__ void nms_kernel(const float* __restrict__ hm1,
                           const float* __restrict__ hm2,
                           unsigned long long* __restrict__ cand) {
    int wid  = blockIdx.x * 4 + (threadIdx.x >> 6);   // 0..4095 global window
    int lane = threadIdx.x & 63;
    int img  = wid >> 10;                             // 0..3 = hm*2 + b
    int win  = wid & 1023;
    int wy = win >> 5, wx = win & 31;
    int py = wy * 8 + (lane >> 3);
    int px = wx * 8 + (lane & 7);
    int b = img & 1;
    const float* hp = ((img >> 1) ? hm2 : hm1) + b * NPIX;
    int fidx = py * WW + px;
    float v = sigmoidf_(hp[fidx]);
    // wave max, smallest-index tie-break
    float mv = v; int mi = fidx;
    #pragma unroll
    for (int m = 1; m <= 32; m <<= 1) {
        float ov = __shfl_xor(mv, m);
        int   oi = __shfl_xor(mi, m);
        if (ov > mv || (ov == mv && oi < mi)) { mv = ov; mi = oi; }
    }
    if (lane == 0) {
        int ay = mi >> 8, ax = mi & 255;
        float val = (ay >= 10 && ay < 246 && ax >= 10 && ax < 246) ? mv : 0.0f;
        unsigned int vb = __float_as_uint(val);   // val >= 0 so bits are order-preserving
        unsigned long long key = ((unsigned long long)vb << 32) |
                                 (unsigned long long)(0xFFFFFFFFu - (unsigned int)mi);
        cand[img * NCAND + win] = key;
    }
}

// ---------------- phase 2: top-512 via bitonic sort of 1024 candidates ----
// grid 4 x 512 threads, one block per image.
__global__ void topk_kernel(const float* __restrict__ hm1,
                            const float* __restrict__ hm2,
                            const unsigned long long* __restrict__ cand,
                            float* __restrict__ out,
                            float* __restrict__ kp_gx,
                            float* __restrict__ kp_gy) {
    __shared__ unsigned long long keys[1024];
    int img = blockIdx.x;
    int t = threadIdx.x;                    // 0..511
    keys[t]       = cand[img * 1024 + t];
    keys[t + 512] = cand[img * 1024 + t + 512];
    for (int size = 2; size <= 1024; size <<= 1) {
        for (int stride = size >> 1; stride > 0; stride >>= 1) {
            __syncthreads();
            int i = ((t / stride) * (stride << 1)) + (t % stride);
            int j = i + stride;
            bool desc = ((i & size) == 0);
            unsigned long long a = keys[i], bb = keys[j];
            if (desc ? (a < bb) : (a > bb)) { keys[i] = bb; keys[j] = a; }
        }
    }
    __syncthreads();
    unsigned long long key = keys[t];
    int fidx = (int)(0xFFFFFFFFu - (unsigned int)(key & 0xFFFFFFFFull));
    int row = fidx >> 8, col = fidx & 255;
    float gx = 2.0f * (float)col / 255.0f - 1.0f;
    float gy = 2.0f * (float)row / 255.0f - 1.0f;
    int hmid = img >> 1, b = img & 1;
    float* lm = out + (hmid ? 4096 : 2048) + (size_t)(b * 512 + t) * 2;
    lm[0] = gx; lm[1] = gy;
    kp_gx[img * 512 + t] = gx;
    kp_gy[img * 512 + t] = gy;
    // probs = bilinear sample of sigmoid heatmap at (gx,gy)
    const float* hp = (hmid ? hm2 : hm1) + b * NPIX;
    float ix = (gx + 1.0f) * 0.5f * 255.0f;
    float iy = (gy + 1.0f) * 0.5f * 255.0f;
    float x0f = floorf(ix), y0f = floorf(iy);
    float wxf = ix - x0f, wyf = iy - y0f;
    int x0 = min(max((int)x0f, 0), 255);
    int x1 = min(max((int)x0f + 1, 0), 255);
    int y0 = min(max((int)y0f, 0), 255);
    int y1 = min(max((int)y0f + 1, 0), 255);
    float v00 = sigmoidf_(hp[y0 * 256 + x0]);
    float v01 = sigmoidf_(hp[y0 * 256 + x1]);
    float v10 = sigmoidf_(hp[y1 * 256 + x0]);
    float v11 = sigmoidf_(hp[y1 * 256 + x1]);
    float pv = v00 * (1 - wxf) * (1 - wyf) + v01 * wxf * (1 - wyf)
             + v10 * (1 - wxf) * wyf       + v11 * wxf * wyf;
    out[hmid * 1024 + b * 512 + t] = pv;
}

// ---------------- phase 3: descriptor gather + norm precompute ----------
// grid 2048 (img*512+k) x 192 threads (one per channel).
__global__ void desc_kernel(const float* __restrict__ f1a, const float* __restrict__ f1b,
                            const float* __restrict__ f2a, const float* __restrict__ f2b,
                            const float* __restrict__ kp_gx, const float* __restrict__ kp_gy,
                            float* __restrict__ dws, float* __restrict__ invws,
                            float* __restrict__ nnws) {
    int blk = blockIdx.x;            // img*512 + k
    int img = blk >> 9;
    int c = threadIdx.x;             // 0..191
    int b = img & 1, hmid = img >> 1;
    float gx = kp_gx[blk], gy = kp_gy[blk];
    const float* base; int dim;
    if (c < 64) {
        const float* fa = hmid ? f2a : f1a;
        base = fa + (size_t)(b * 64 + c) * 65536; dim = 256;
    } else {
        const float* fb = hmid ? f2b : f1b;
        base = fb + (size_t)(b * 128 + (c - 64)) * 16384; dim = 128;
    }
    float ix = (gx + 1.0f) * 0.5f * (float)(dim - 1);
    float iy = (gy + 1.0f) * 0.5f * (float)(dim - 1);
    float x0f = floorf(ix), y0f = floorf(iy);
    float wx = ix - x0f, wy = iy - y0f;
    int x0 = min(max((int)x0f, 0), dim - 1);
    int x1 = min(max((int)x0f + 1, 0), dim - 1);
    int y0 = min(max((int)y0f, 0), dim - 1);
    int y1 = min(max((int)y0f + 1, 0), dim - 1);
    float v00 = base[y0 * dim + x0], v01 = base[y0 * dim + x1];
    float v10 = base[y1 * dim + x0], v11 = base[y1 * dim + x1];
    float val = v00 * (1 - wx) * (1 - wy) + v01 * wx * (1 - wy)
              + v10 * (1 - wx) * wy       + v11 * wx * wy;
    dws[(size_t)blk * 192 + c] = val;
    float sq = val * val;
    #pragma unroll
    for (int m = 1; m <= 32; m <<= 1) sq += __shfl_xor(sq, m);
    __shared__ float part[3];
    if ((threadIdx.x & 63) == 0) part[threadIdx.x >> 6] = sq;
    __syncthreads();
    if (threadIdx.x == 0) {
        float ss = part[0] + part[1] + part[2];
        float nrm = sqrtf(ss);
        float inv = 1.0f / (1e-6f + nrm);
        invws[blk] = inv;
        nnws[blk] = ss * inv * inv;   // ||n||^2
    }
}

// ---------------- phase 4: pairwise matching -----------------------------
// grid (16,16,2), 256 threads; 32x32 output tile per block, 2x2 per thread.
__global__ __launch_bounds__(256) void match_kernel(
    const float* __restrict__ dws, const float* __restrict__ invws,
    const float* __restrict__ nnws, const float* __restrict__ fcw,
    const float* __restrict__ fcb, float* __restrict__ out) {
    __shared__ float As[32][33];
    __shared__ float Bs[32][33];
    __shared__ float w0s[192], w1s[192];
    int b = blockIdx.z;
    int k1base = blockIdx.y * 32;
    int k2base = blockIdx.x * 32;
    int t = threadIdx.x;
    int tx = t & 15, ty = t >> 4;
    if (t < 192) { w0s[t] = fcw[t]; w1s[t] = fcw[192 + t]; }
    const float* d1 = dws + (size_t)(b * 512 + k1base) * 192;       // img = b
    const float* d2 = dws + (size_t)((2 + b) * 512 + k2base) * 192; // img = 2+b
    float dot[2][2] = {{0,0},{0,0}}, s0[2][2] = {{0,0},{0,0}}, s1[2][2] = {{0,0},{0,0}};
    for (int cb = 0; cb < 192; cb += 32) {
        __syncthreads();
        #pragma unroll
        for (int l = 0; l < 4; ++l) {
            int e = t + 256 * l;
            int r = e >> 5, cc = e & 31;
            As[r][cc] = d1[r * 192 + cb + cc];
            Bs[r][cc] = d2[r * 192 + cb + cc];
        }
        __syncthreads();
        #pragma unroll
        for (int cc = 0; cc < 32; ++cc) {
            float w0c = w0s[cb + cc], w1c = w1s[cb + cc];
            float a0 = As[ty][cc],      a1v = As[ty + 16][cc];
            float b0 = Bs[tx][cc],      b1v = Bs[tx + 16][cc];
            float aw00 = a0 * w0c, aw01 = a1v * w0c;
            float aw10 = a0 * w1c, aw11 = a1v * w1c;
            dot[0][0] += a0 * b0;   dot[0][1] += a0 * b1v;
            dot[1][0] += a1v * b0;  dot[1][1] += a1v * b1v;
            s0[0][0] += aw00 * b0;  s0[0][1] += aw00 * b1v;
            s0[1][0] += aw01 * b0;  s0[1][1] += aw01 * b1v;
            s1[0][0] += aw10 * b0;  s1[0][1] += aw10 * b1v;
            s1[1][0] += aw11 * b0;  s1[1][1] += aw11 * b1v;
        }
    }
    float bb0 = fcb[0], bb1 = fcb[1];
    #pragma unroll
    for (int i = 0; i < 2; ++i) {
        int k1 = k1base + ty + 16 * i;
        float inv1 = invws[b * 512 + k1];
        float nn1  = nnws[b * 512 + k1];
        #pragma unroll
        for (int j = 0; j < 2; ++j) {
            int k2 = k2base + tx + 16 * j;
            float inv2 = invws[(2 + b) * 512 + k2];
            float nn2  = nnws[(2 + b) * 512 + k2];
            size_t sidx = (size_t)(b * 512 + k1) * 512 + k2;
            float2 sc = make_float2(s0[i][j] + bb0, s1[i][j] + bb1);
            *reinterpret_cast<float2*>(out + 6144 + sidx * 2) = sc;
            float arg = nn1 + nn2 - 2.0f * inv1 * inv2 * dot[i][j];
            out[1054720 + sidx] = sqrtf(fmaxf(arg, 0.0f));
        }
    }
}

extern "C" void kernel_launch(void* const* d_in, const int* in_sizes, int n_in,
                              void* d_out, int out_size, void* d_ws, size_t ws_size,
                              hipStream_t stream) {
    const float* hm1 = (const float*)d_in[0];
    const float* hm2 = (const float*)d_in[1];
    const float* f1a = (const float*)d_in[2];
    const float* f1b = (const float*)d_in[3];
    const float* f2a = (const float*)d_in[4];
    const float* f2b = (const float*)d_in[5];
    const float* fcw = (const float*)d_in[6];
    const float* fcb = (const float*)d_in[7];
    float* out = (float*)d_out;
    char* ws = (char*)d_ws;

    unsigned long long* cand = (unsigned long long*)ws;   // 4*1024*8 = 32768 B
    float* kp_gx = (float*)(ws + 32768);                  // 8192 B
    float* kp_gy = (float*)(ws + 40960);                  // 8192 B
    float* invws = (float*)(ws + 49152);                  // 8192 B
    float* nnws  = (float*)(ws + 57344);                  // 8192 B
    float* dws   = (float*)(ws + 65536);                  // 4*512*192*4 = 1572864 B

    nms_kernel<<<1024, 256, 0, stream>>>(hm1, hm2, cand);
    topk_kernel<<<4, 512, 0, stream>>>(hm1, hm2, cand, out, kp_gx, kp_gy);
    desc_kernel<<<2048, 192, 0, stream>>>(f1a, f1b, f2a, f2b, kp_gx, kp_gy,
                                          dws, invws, nnws);
    dim3 g(16, 16, 2);
    match_kernel<<<g, 256, 0, stream>>>(dws, invws, nnws, fcw, fcb, out);
}

// Round 2
// 58.370 us; speedup vs baseline: 1.0385x; 1.0385x over previous
//
#include <hip/hip_runtime.h>
#include <math.h>

#define NPIX 65536

__device__ __forceinline__ float sigmoidf_(float x) {
    return 1.0f / (1.0f + expf(-x));
}

__device__ __forceinline__ unsigned long long u64min(unsigned long long a, unsigned long long b) {
    return a < b ? a : b;
}
__device__ __forceinline__ unsigned long long u64max(unsigned long long a, unsigned long long b) {
    return a > b ? a : b;
}

// ---------------- phase 1: fused NMS + top-512 ----------------
// grid 4 (one block per image) x 1024 threads; thread t owns 8x8 window t,
// then a 1024-key bitonic sort (1 key/thread): strides<=32 via shfl_xor,
// strides 64..512 via LDS (10 LDS stages instead of 55).
__global__ __launch_bounds__(1024) void nms_topk_kernel(
        const float* __restrict__ hm1, const float* __restrict__ hm2,
        float* __restrict__ out, int* __restrict__ kp_idx) {
    __shared__ unsigned long long keys[1024];
    int img = blockIdx.x;             // hm*2 + b
    int t = threadIdx.x;              // window id 0..1023
    int b = img & 1, hmid = img >> 1;
    const float* hp = (hmid ? hm2 : hm1) + b * NPIX;

    // --- NMS for window t: row-major scan, sigmoid compare, earliest-index tie-break
    int wy = t >> 5, wx = t & 31;
    const float* wp = hp + wy * 8 * 256 + wx * 8;
    float mv = -1.0f;
    int mi = 0;
    #pragma unroll
    for (int r = 0; r < 8; ++r) {
        float4 v0 = *reinterpret_cast<const float4*>(wp + r * 256);
        float4 v1 = *reinterpret_cast<const float4*>(wp + r * 256 + 4);
        float s[8];
        s[0] = sigmoidf_(v0.x); s[1] = sigmoidf_(v0.y);
        s[2] = sigmoidf_(v0.z); s[3] = sigmoidf_(v0.w);
        s[4] = sigmoidf_(v1.x); s[5] = sigmoidf_(v1.y);
        s[6] = sigmoidf_(v1.z); s[7] = sigmoidf_(v1.w);
        int rowbase = (wy * 8 + r) * 256 + wx * 8;
        #pragma unroll
        for (int cidx = 0; cidx < 8; ++cidx) {
            if (s[cidx] > mv) { mv = s[cidx]; mi = rowbase + cidx; }
        }
    }
    int ay = mi >> 8, ax = mi & 255;
    float val = (ay >= 10 && ay < 246 && ax >= 10 && ax < 246) ? mv : 0.0f;
    // ascending sort key: smallest key = largest val, ties -> smallest idx
    unsigned int vb = __float_as_uint(val);          // val >= 0: order-preserving bits
    unsigned long long k = ((unsigned long long)(vb ^ 0xFFFFFFFFu) << 32) |
                           (unsigned long long)(unsigned int)mi;

    // --- bitonic sort, ascending
    for (int size = 2; size <= 1024; size <<= 1) {
        for (int stride = size >> 1; stride >= 1; stride >>= 1) {
            bool dir_up = ((t & size) == 0);
            unsigned long long pk;
            if (stride >= 64) {
                __syncthreads();
                keys[t] = k;
                __syncthreads();
                pk = keys[t ^ stride];
            } else {
                pk = __shfl_xor(k, stride);
            }
            bool low = ((t & stride) == 0);
            k = ((low == dir_up)) ? u64min(k, pk) : u64max(k, pk);
        }
    }

    // --- emit rank t (t < 512)
    if (t < 512) {
        unsigned int fidx = (unsigned int)(k & 0xFFFFFFFFull);
        float v = __uint_as_float(0xFFFFFFFFu ^ (unsigned int)(k >> 32));
        int row = fidx >> 8, col = fidx & 255;
        float gx = 2.0f * (float)col / 255.0f - 1.0f;
        float gy = 2.0f * (float)row / 255.0f - 1.0f;
        // probs: keypoints sit on exact pixel centers -> bilinear == h[row,col] == v
        out[hmid * 1024 + b * 512 + t] = v;
        float* lm = out + (hmid ? 4096 : 2048) + (size_t)(b * 512 + t) * 2;
        lm[0] = gx; lm[1] = gy;
        kp_idx[img * 512 + t] = (int)fidx;
    }
}

// ---------------- phase 2: descriptor gather + norm precompute ----------
// grid 2048 (img*512+k) x 192 threads (one per channel).
// c<64: keypoint is on an exact pixel of the 256x256 grid -> direct load.
// c>=64: true bilinear on the 128x128 grid.
__global__ void desc_kernel(const float* __restrict__ f1a, const float* __restrict__ f1b,
                            const float* __restrict__ f2a, const float* __restrict__ f2b,
                            const int* __restrict__ kp_idx,
                            float* __restrict__ dws, float* __restrict__ invws,
                            float* __restrict__ nnws) {
    int blk = blockIdx.x;            // img*512 + k
    int img = blk >> 9;
    int c = threadIdx.x;             // 0..191
    int b = img & 1, hmid = img >> 1;
    int fidx = kp_idx[blk];
    int row = fidx >> 8, col = fidx & 255;
    float val;
    if (c < 64) {
        const float* fa = hmid ? f2a : f1a;
        val = fa[(size_t)(b * 64 + c) * 65536 + fidx];
    } else {
        const float* fb = hmid ? f2b : f1b;
        const float* base = fb + (size_t)(b * 128 + (c - 64)) * 16384;
        float gx = 2.0f * (float)col / 255.0f - 1.0f;
        float gy = 2.0f * (float)row / 255.0f - 1.0f;
        float ix = (gx + 1.0f) * 0.5f * 127.0f;
        float iy = (gy + 1.0f) * 0.5f * 127.0f;
        float x0f = floorf(ix), y0f = floorf(iy);
        float wx = ix - x0f, wy = iy - y0f;
        int x0 = min(max((int)x0f, 0), 127);
        int x1 = min(max((int)x0f + 1, 0), 127);
        int y0 = min(max((int)y0f, 0), 127);
        int y1 = min(max((int)y0f + 1, 0), 127);
        float v00 = base[y0 * 128 + x0], v01 = base[y0 * 128 + x1];
        float v10 = base[y1 * 128 + x0], v11 = base[y1 * 128 + x1];
        val = v00 * (1 - wx) * (1 - wy) + v01 * wx * (1 - wy)
            + v10 * (1 - wx) * wy       + v11 * wx * wy;
    }
    dws[(size_t)blk * 192 + c] = val;
    float sq = val * val;
    #pragma unroll
    for (int m = 1; m <= 32; m <<= 1) sq += __shfl_xor(sq, m);
    __shared__ float part[3];
    if ((threadIdx.x & 63) == 0) part[threadIdx.x >> 6] = sq;
    __syncthreads();
    if (threadIdx.x == 0) {
        float ss = part[0] + part[1] + part[2];
        float nrm = sqrtf(ss);
        float inv = 1.0f / (1e-6f + nrm);
        invws[blk] = inv;
        nnws[blk] = ss * inv * inv;   // ||n||^2
    }
}

// ---------------- phase 3: pairwise matching -----------------------------
// grid (16,16,2), 256 threads; 32x32 output tile per block, 2x2 per thread.
__global__ __launch_bounds__(256) void match_kernel(
    const float* __restrict__ dws, const float* __restrict__ invws,
    const float* __restrict__ nnws, const float* __restrict__ fcw,
    const float* __restrict__ fcb, float* __restrict__ out) {
    __shared__ float As[32][33];
    __shared__ float Bs[32][33];
    __shared__ float w0s[192], w1s[192];
    int b = blockIdx.z;
    int k1base = blockIdx.y * 32;
    int k2base = blockIdx.x * 32;
    int t = threadIdx.x;
    int tx = t & 15, ty = t >> 4;
    if (t < 192) { w0s[t] = fcw[t]; w1s[t] = fcw[192 + t]; }
    const float* d1 = dws + (size_t)(b * 512 + k1base) * 192;       // img = b
    const float* d2 = dws + (size_t)((2 + b) * 512 + k2base) * 192; // img = 2+b
    float dot[2][2] = {{0,0},{0,0}}, s0[2][2] = {{0,0},{0,0}}, s1[2][2] = {{0,0},{0,0}};
    for (int cb = 0; cb < 192; cb += 32) {
        __syncthreads();
        #pragma unroll
        for (int l = 0; l < 4; ++l) {
            int e = t + 256 * l;
            int r = e >> 5, cc = e & 31;
            As[r][cc] = d1[r * 192 + cb + cc];
            Bs[r][cc] = d2[r * 192 + cb + cc];
        }
        __syncthreads();
        #pragma unroll
        for (int cc = 0; cc < 32; ++cc) {
            float w0c = w0s[cb + cc], w1c = w1s[cb + cc];
            float a0 = As[ty][cc],      a1v = As[ty + 16][cc];
            float b0 = Bs[tx][cc],      b1v = Bs[tx + 16][cc];
            float aw00 = a0 * w0c, aw01 = a1v * w0c;
            float aw10 = a0 * w1c, aw11 = a1v * w1c;
            dot[0][0] += a0 * b0;   dot[0][1] += a0 * b1v;
            dot[1][0] += a1v * b0;  dot[1][1] += a1v * b1v;
            s0[0][0] += aw00 * b0;  s0[0][1] += aw00 * b1v;
            s0[1][0] += aw01 * b0;  s0[1][1] += aw01 * b1v;
            s1[0][0] += aw10 * b0;  s1[0][1] += aw10 * b1v;
            s1[1][0] += aw11 * b0;  s1[1][1] += aw11 * b1v;
        }
    }
    float bb0 = fcb[0], bb1 = fcb[1];
    #pragma unroll
    for (int i = 0; i < 2; ++i) {
        int k1 = k1base + ty + 16 * i;
        float inv1 = invws[b * 512 + k1];
        float nn1  = nnws[b * 512 + k1];
        #pragma unroll
        for (int j = 0; j < 2; ++j) {
            int k2 = k2base + tx + 16 * j;
            float inv2 = invws[(2 + b) * 512 + k2];
            float nn2  = nnws[(2 + b) * 512 + k2];
            size_t sidx = (size_t)(b * 512 + k1) * 512 + k2;
            float2 sc = make_float2(s0[i][j] + bb0, s1[i][j] + bb1);
            *reinterpret_cast<float2*>(out + 6144 + sidx * 2) = sc;
            float arg = nn1 + nn2 - 2.0f * inv1 * inv2 * dot[i][j];
            out[1054720 + sidx] = sqrtf(fmaxf(arg, 0.0f));
        }
    }
}

extern "C" void kernel_launch(void* const* d_in, const int* in_sizes, int n_in,
                              void* d_out, int out_size, void* d_ws, size_t ws_size,
                              hipStream_t stream) {
    const float* hm1 = (const float*)d_in[0];
    const float* hm2 = (const float*)d_in[1];
    const float* f1a = (const float*)d_in[2];
    const float* f1b = (const float*)d_in[3];
    const float* f2a = (const float*)d_in[4];
    const float* f2b = (const float*)d_in[5];
    const float* fcw = (const float*)d_in[6];
    const float* fcb = (const float*)d_in[7];
    float* out = (float*)d_out;
    char* ws = (char*)d_ws;

    int*   kp_idx = (int*)ws;                  // 2048*4 = 8192 B
    float* invws  = (float*)(ws + 8192);       // 8192 B
    float* nnws   = (float*)(ws + 16384);      // 8192 B
    float* dws    = (float*)(ws + 24576);      // 4*512*192*4 = 1572864 B

    nms_topk_kernel<<<4, 1024, 0, stream>>>(hm1, hm2, out, kp_idx);
    desc_kernel<<<2048, 192, 0, stream>>>(f1a, f1b, f2a, f2b, kp_idx,
                                          dws, invws, nnws);
    dim3 g(16, 16, 2);
    match_kernel<<<g, 256, 0, stream>>>(dws, invws, nnws, fcw, fcb, out);
}